// Round 1
// baseline (3638.495 us; speedup 1.0000x reference)
//
#include <hip/hip_runtime.h>
#include <hip/hip_bf16.h>

// WaveOperator: Fourier-domain 3-term recurrence + per-row inverse FFT sampling.
// A_{t+1}(p,q) = (2-4*fil(p,q)) * A_t - A_{t-1};  y[b,j,t] = Re(ifft2(A_{t+1})[u_j,v_j])
// Blocks keep 4 rows x 2 time levels of A resident in LDS for a whole time chunk.

#define NOUT 512
#define NB 16
#define NPHI 256
#define NT 240

// ---------------- in-register 512-point inverse DFT (unnormalized, exp(+2pi i qk/512)) -----------
// layout: lane L (0..63) holds elements e = r*64 + L, r = 0..7. DIF, output bit-reversed:
// after the 9 stages, element e holds X[bitrev9(e)].

__device__ __forceinline__ void cbfly(float& ar, float& ai, float& br, float& bi,
                                      float wr, float wi) {
    float dr = ar - br, di = ai - bi;
    ar = ar + br; ai = ai + bi;
    br = fmaf(dr, wr, -di * wi);
    bi = fmaf(dr, wi,  di * wr);
}

__device__ __forceinline__ void fft512_inv(float* xr, float* xi, const float2* trig, int L) {
    // stage 0: half=256, pairs (r, r+4), exp = 64*r + L  (< 256)
#pragma unroll
    for (int r = 0; r < 4; ++r) {
        float2 w = trig[(r << 6) + L];
        cbfly(xr[r], xi[r], xr[r + 4], xi[r + 4], w.x, w.y);
    }
    // stage 1: half=128, pairs (0,2),(1,3),(4,6),(5,7), exp = ((r&1)*64 + L) << 1
    {
        float2 w0 = trig[L << 1];
        float2 w1 = trig[(64 + L) << 1];
        cbfly(xr[0], xi[0], xr[2], xi[2], w0.x, w0.y);
        cbfly(xr[1], xi[1], xr[3], xi[3], w1.x, w1.y);
        cbfly(xr[4], xi[4], xr[6], xi[6], w0.x, w0.y);
        cbfly(xr[5], xi[5], xr[7], xi[7], w1.x, w1.y);
    }
    // stage 2: half=64, pairs (0,1),(2,3),(4,5),(6,7), exp = L << 2
    {
        float2 w = trig[L << 2];
        cbfly(xr[0], xi[0], xr[1], xi[1], w.x, w.y);
        cbfly(xr[2], xi[2], xr[3], xi[3], w.x, w.y);
        cbfly(xr[4], xi[4], xr[5], xi[5], w.x, w.y);
        cbfly(xr[6], xi[6], xr[7], xi[7], w.x, w.y);
    }
    // stages 3..8: cross-lane via shfl_xor, half = 32,16,8,4,2,1, exp = (L & (half-1)) << s
#pragma unroll
    for (int s = 3; s <= 8; ++s) {
        const int half = 512 >> (s + 1);
        const int ex = (L & (half - 1)) << s;
        float2 w = trig[ex];
        const bool hi = (L & half) != 0;
        float wr = hi ? w.x : 1.0f;
        float wi = hi ? w.y : 0.0f;
        float sg = hi ? -1.0f : 1.0f;
#pragma unroll
        for (int r = 0; r < 8; ++r) {
            float orv = __shfl_xor(xr[r], half);
            float oiv = __shfl_xor(xi[r], half);
            float tr = fmaf(sg, xr[r], orv);   // lo: x+other, hi: other-x
            float ti = fmaf(sg, xi[r], oiv);
            xr[r] = fmaf(tr, wr, -ti * wi);
            xi[r] = fmaf(tr, wi,  ti * wr);
        }
    }
}

__device__ __forceinline__ void init_trig(float2* trig, int tid) {
    if (tid < 256) {
        float ang = (float)tid * (6.283185307179586f / 512.0f);
        float s, c;
        sincosf(ang, &s, &c);
        trig[tid] = make_float2(c, s);
    }
}

// ---------------- initial forward FFT, pass 1: rows (axis y) of padded f -> R[b][x][k] ------------
__global__ __launch_bounds__(256) void f1_kernel(const float* __restrict__ f,
                                                 float2* __restrict__ R) {
    __shared__ float2 trig[256];
    const int tid = threadIdx.x;
    init_trig(trig, tid);
    __syncthreads();
    const int w = tid >> 6, L = tid & 63;
    const int x = 128 + blockIdx.x * 4 + w;   // nonzero rows only: [128, 384)
    const int b = blockIdx.y;
    const float* frow = f + ((size_t)b * 256 + (x - 128)) * 256;
    float xr[8], xi[8];
#pragma unroll
    for (int r = 0; r < 8; ++r) {
        int e = r * 64 + L;
        xr[r] = (e >= 128 && e < 384) ? frow[e - 128] : 0.0f;
        xi[r] = 0.0f;
    }
    fft512_inv(xr, xi, trig, L);
    // forward FFT of real input = conj(inverse FFT)
    float2* Rrow = R + ((size_t)b * NOUT + x) * NOUT;
#pragma unroll
    for (int r = 0; r < 8; ++r) {
        int e = r * 64 + L;
        int k = __brev((unsigned)e) >> 23;
        Rrow[k] = make_float2(xr[r], -xi[r]);
    }
}

// ---------------- initial forward FFT, pass 2: columns (axis x) -> A0[b][p][q] --------------------
__global__ __launch_bounds__(256) void f2_kernel(const float2* __restrict__ R,
                                                 float2* __restrict__ A0) {
    __shared__ float2 trig[256];
    const int tid = threadIdx.x;
    init_trig(trig, tid);
    __syncthreads();
    const int w = tid >> 6, L = tid & 63;
    const int q = blockIdx.x * 4 + w;         // 0..511
    const int b = blockIdx.y;
    float xr[8], xi[8];
#pragma unroll
    for (int r = 0; r < 8; ++r) {
        int e = r * 64 + L;
        float2 v = R[((size_t)b * NOUT + e) * NOUT + q];
        xr[r] = v.x;
        xi[r] = -v.y;   // conj input
    }
    fft512_inv(xr, xi, trig, L);
#pragma unroll
    for (int r = 0; r < 8; ++r) {
        int e = r * 64 + L;
        int p = __brev((unsigned)e) >> 23;
        A0[((size_t)b * NOUT + p) * NOUT + q] = make_float2(xr[r], -xi[r]); // conj output
    }
}

// ---------------- time-chunk simulation: LDS-resident state, per-step row FFT + sampling ----------
// block = (row group g of 4 rows, batch b); wave w owns row p = 4g + w.
__global__ __launch_bounds__(256) void sim_kernel(
    const float* __restrict__ fil,
    const int* __restrict__ idx0, const int* __restrict__ idx1,
    float2* __restrict__ stateCur, float2* __restrict__ statePrev,
    float* __restrict__ partial, int Tc, int firstChunk)
{
    __shared__ float2 A[4][2][NOUT];     // 32768 B : two time levels per row
    __shared__ float  C[4][NOUT];        //  8192 B : c = 2 - 4*fil
    __shared__ float2 T[4][NOUT];        // 16384 B : per-row inverse-DFT result (bitrev positions)
    __shared__ float2 trig[256];         //  2048 B
    __shared__ unsigned upos[NPHI];      //  1024 B : idx0 | (bitrev9(idx1) << 16)
    __shared__ float  ystep[4][NPHI];    //  4096 B : per-wave sensor contributions
                                         // total 64512 B

    const int tid = threadIdx.x;
    const int w = tid >> 6, L = tid & 63;
    const int g = blockIdx.x, b = blockIdx.y;
    const int p = g * 4 + w;

    init_trig(trig, tid);
    if (tid < NPHI) {
        unsigned pos = __brev((unsigned)idx1[tid]) >> 23;
        upos[tid] = ((unsigned)idx0[tid]) | (pos << 16);
    }
    {
        const float2* curRow  = stateCur  + ((size_t)b * NOUT + p) * NOUT;
        const float2* prevRow = statePrev + ((size_t)b * NOUT + p) * NOUT;
        const float*  filRow  = fil + (size_t)p * NOUT;
#pragma unroll
        for (int r = 0; r < 8; ++r) {
            int e = r * 64 + L;
            float2 a0 = curRow[e];
            A[w][0][e] = a0;
            A[w][1][e] = firstChunk ? a0 : prevRow[e];
            C[w][e] = fmaf(-4.0f, filRow[e], 2.0f);
        }
    }
    __syncthreads();

    int cur = 0;   // A[w][cur] = A_t, A[w][cur^1] = A_{t-1}
    for (int tl = 0; tl < Tc; ++tl) {
        float xr[8], xi[8];
#pragma unroll
        for (int r = 0; r < 8; ++r) {
            int e = r * 64 + L;
            float2 at = A[w][cur][e];
            float2 ao = A[w][cur ^ 1][e];
            float c = C[w][e];
            float nr = fmaf(c, at.x, -ao.x);
            float ni = fmaf(c, at.y, -ao.y);
            A[w][cur ^ 1][e] = make_float2(nr, ni);   // becomes A_{t+1}
            xr[r] = nr; xi[r] = ni;
        }
        cur ^= 1;
        fft512_inv(xr, xi, trig, L);   // T(p, v) at position bitrev9(v)
#pragma unroll
        for (int r = 0; r < 8; ++r) T[w][r * 64 + L] = make_float2(xr[r], xi[r]);
        __syncthreads();
        // sensor contributions of this row: Re( T(p, v_j) * e^{2pi i p u_j / 512} )
#pragma unroll
        for (int jj = 0; jj < 4; ++jj) {
            int j = (jj << 6) + L;
            unsigned up = upos[j];
            int u = up & 0xffffu;
            int pos = up >> 16;
            float2 t2 = T[w][pos];
            int m = (p * u) & 511;
            float2 ph = trig[m & 255];
            float contrib = fmaf(t2.x, ph.x, -t2.y * ph.y);
            ystep[w][j] = (m & 256) ? -contrib : contrib;
        }
        __syncthreads();
        if (w == 0) {
#pragma unroll
            for (int jj = 0; jj < 4; ++jj) {
                int j = (jj << 6) + L;
                float v = ystep[0][j] + ystep[1][j] + ystep[2][j] + ystep[3][j];
                partial[(((size_t)g * Tc + tl) * NB + b) * NPHI + j] = v;
            }
        }
        // waves 1..3 proceed; their next ystep writes happen only after the next
        // post-FFT __syncthreads, which wave 0 reaches after finishing its reads.
    }
    __syncthreads();
    {
        float2* curRow  = stateCur  + ((size_t)b * NOUT + p) * NOUT;
        float2* prevRow = statePrev + ((size_t)b * NOUT + p) * NOUT;
#pragma unroll
        for (int r = 0; r < 8; ++r) {
            int e = r * 64 + L;
            curRow[e]  = A[w][cur][e];
            prevRow[e] = A[w][cur ^ 1][e];
        }
    }
}

// ---------------- reduce 128 row-group partials -> out[b][j][t] -----------------------------------
__global__ __launch_bounds__(256) void reduce_kernel(const float* __restrict__ partial,
                                                     float* __restrict__ out,
                                                     int Tc, int tStart) {
    int id = blockIdx.x * 256 + threadIdx.x;   // over Tc*16*256, exact
    int j = id & 255;
    int b = (id >> 8) & 15;
    int tl = id >> 12;
    float s = 0.0f;
#pragma unroll 8
    for (int gg = 0; gg < 128; ++gg)
        s += partial[(((size_t)gg * Tc + tl) * NB + b) * NPHI + j];
    out[((size_t)b * NPHI + j) * NT + (tStart + tl)] = s * (1.0f / (512.0f * 512.0f));
}

extern "C" void kernel_launch(void* const* d_in, const int* in_sizes, int n_in,
                              void* d_out, int out_size, void* d_ws, size_t ws_size,
                              hipStream_t stream) {
    (void)in_sizes; (void)n_in; (void)out_size;
    const float* f   = (const float*)d_in[0];   // [16,1,256,256]
    const float* fil = (const float*)d_in[1];   // [512,512]
    const int* idx0  = (const int*)d_in[2];     // [256]
    const int* idx1  = (const int*)d_in[3];     // [256]
    float* out = (float*)d_out;                 // [16,1,256,240]

    char* ws = (char*)d_ws;
    const size_t stateBytes = (size_t)NB * NOUT * NOUT * sizeof(float2);  // 33.55 MB
    float2* stateCur  = (float2*)ws;
    float2* statePrev = (float2*)(ws + stateBytes);   // also reused as R scratch for f1/f2
    float*  partial   = (float*)(ws + 2 * stateBytes);
    size_t remain = (ws_size > 2 * stateBytes) ? ws_size - 2 * stateBytes : 0;

    // choose largest time chunk whose partial buffer fits in remaining workspace
    static const int tcs[] = {240, 120, 80, 60, 48, 40, 30, 24, 20, 16, 12, 10, 8, 6, 4, 2, 1};
    int Tc = 1;
    for (int i = 0; i < 17; ++i) {
        size_t need = (size_t)128 * tcs[i] * NB * NPHI * sizeof(float);
        if (need <= remain) { Tc = tcs[i]; break; }
    }

    hipMemsetAsync(statePrev, 0, stateBytes, stream);                 // zero-padded rows of R
    f1_kernel<<<dim3(64, NB), 256, 0, stream>>>(f, statePrev);        // rows x in [128,384)
    f2_kernel<<<dim3(128, NB), 256, 0, stream>>>(statePrev, stateCur);
    for (int t0 = 0; t0 < NT; t0 += Tc) {
        sim_kernel<<<dim3(128, NB), 256, 0, stream>>>(fil, idx0, idx1, stateCur, statePrev,
                                                      partial, Tc, t0 == 0 ? 1 : 0);
        reduce_kernel<<<dim3(Tc * NB), 256, 0, stream>>>(partial, out, Tc, t0);
    }
}

// Round 2
// 2956.942 us; speedup vs baseline: 1.2305x; 1.2305x over previous
//
#include <hip/hip_runtime.h>
#include <hip/hip_bf16.h>

// WaveOperator: Fourier-domain 3-term recurrence + per-row inverse FFT sampling.
// A_{t+1}(p,q) = (2-4*fil(p,q)) * A_t - A_{t-1};  y[b,j,t] = Re(ifft2(A_{t+1})[u_j,v_j])
// R2: A-state, filter coeffs, FFT twiddles, and sensor phases all live in REGISTERS;
// LDS holds only the per-row FFT result T (for the random sensor gather) + init trig.

#define NOUT 512
#define NB 16
#define NPHI 256
#define NT 240

// ---------------- shared helpers ------------------------------------------------------------------

__device__ __forceinline__ void cbfly(float& ar, float& ai, float& br, float& bi,
                                      float wr, float wi) {
    float dr = ar - br, di = ai - bi;
    ar = ar + br; ai = ai + bi;
    br = fmaf(dr, wr, -di * wi);
    bi = fmaf(dr, wi,  di * wr);
}

__device__ __forceinline__ void init_trig(float2* trig, int tid) {
    if (tid < 256) {
        float ang = (float)tid * (6.283185307179586f / 512.0f);
        float s, c;
        sincosf(ang, &s, &c);
        trig[tid] = make_float2(c, s);
    }
}

// ---------------- 512-pt inverse DFT, LDS twiddles (init kernels only) ----------------------------
// lane L holds elements e = r*64 + L. DIF; output at bit-reversed positions.
__device__ __forceinline__ void fft512_inv_lds(float* xr, float* xi, const float2* trig, int L) {
#pragma unroll
    for (int r = 0; r < 4; ++r) {
        float2 w = trig[(r << 6) + L];
        cbfly(xr[r], xi[r], xr[r + 4], xi[r + 4], w.x, w.y);
    }
    {
        float2 w0 = trig[L << 1];
        float2 w1 = trig[(64 + L) << 1];
        cbfly(xr[0], xi[0], xr[2], xi[2], w0.x, w0.y);
        cbfly(xr[1], xi[1], xr[3], xi[3], w1.x, w1.y);
        cbfly(xr[4], xi[4], xr[6], xi[6], w0.x, w0.y);
        cbfly(xr[5], xi[5], xr[7], xi[7], w1.x, w1.y);
    }
    {
        float2 w = trig[L << 2];
        cbfly(xr[0], xi[0], xr[1], xi[1], w.x, w.y);
        cbfly(xr[2], xi[2], xr[3], xi[3], w.x, w.y);
        cbfly(xr[4], xi[4], xr[5], xi[5], w.x, w.y);
        cbfly(xr[6], xi[6], xr[7], xi[7], w.x, w.y);
    }
#pragma unroll
    for (int s = 3; s <= 8; ++s) {
        const int half = 512 >> (s + 1);
        const int ex = (L & (half - 1)) << s;
        float2 w = trig[ex];
        const bool hi = (L & half) != 0;
        float wr = hi ? w.x : 1.0f;
        float wi = hi ? w.y : 0.0f;
        float sg = hi ? -1.0f : 1.0f;
#pragma unroll
        for (int r = 0; r < 8; ++r) {
            float orv = __shfl_xor(xr[r], half);
            float oiv = __shfl_xor(xi[r], half);
            float tr = fmaf(sg, xr[r], orv);
            float ti = fmaf(sg, xi[r], oiv);
            xr[r] = fmaf(tr, wr, -ti * wi);
            xi[r] = fmaf(tr, wi,  ti * wr);
        }
    }
}

// ---------------- 512-pt inverse DFT, register twiddles (sim hot loop) ----------------------------
__device__ __forceinline__ void fft512_inv_reg(float* xr, float* xi,
                                               const float2* tw0,           // [4]
                                               float2 tw1a, float2 tw1b, float2 tw2,
                                               const float2* tws,           // [6]
                                               const float* sgs) {          // [6]
#pragma unroll
    for (int r = 0; r < 4; ++r)
        cbfly(xr[r], xi[r], xr[r + 4], xi[r + 4], tw0[r].x, tw0[r].y);
    cbfly(xr[0], xi[0], xr[2], xi[2], tw1a.x, tw1a.y);
    cbfly(xr[1], xi[1], xr[3], xi[3], tw1b.x, tw1b.y);
    cbfly(xr[4], xi[4], xr[6], xi[6], tw1a.x, tw1a.y);
    cbfly(xr[5], xi[5], xr[7], xi[7], tw1b.x, tw1b.y);
    cbfly(xr[0], xi[0], xr[1], xi[1], tw2.x, tw2.y);
    cbfly(xr[2], xi[2], xr[3], xi[3], tw2.x, tw2.y);
    cbfly(xr[4], xi[4], xr[5], xi[5], tw2.x, tw2.y);
    cbfly(xr[6], xi[6], xr[7], xi[7], tw2.x, tw2.y);
#pragma unroll
    for (int s = 3; s <= 8; ++s) {
        const int half = 512 >> (s + 1);
        const float wr = tws[s - 3].x, wi = tws[s - 3].y, sg = sgs[s - 3];
#pragma unroll
        for (int r = 0; r < 8; ++r) {
            float orv = __shfl_xor(xr[r], half);
            float oiv = __shfl_xor(xi[r], half);
            float tr = fmaf(sg, xr[r], orv);
            float ti = fmaf(sg, xi[r], oiv);
            xr[r] = fmaf(tr, wr, -ti * wi);
            xi[r] = fmaf(tr, wi,  ti * wr);
        }
    }
}

// ---------------- initial forward FFT, pass 1: rows (axis y) of padded f -> R[b][x][k] ------------
__global__ __launch_bounds__(256) void f1_kernel(const float* __restrict__ f,
                                                 float2* __restrict__ R) {
    __shared__ float2 trig[256];
    const int tid = threadIdx.x;
    init_trig(trig, tid);
    __syncthreads();
    const int w = tid >> 6, L = tid & 63;
    const int x = 128 + blockIdx.x * 4 + w;   // nonzero rows only: [128, 384)
    const int b = blockIdx.y;
    const float* frow = f + ((size_t)b * 256 + (x - 128)) * 256;
    float xr[8], xi[8];
#pragma unroll
    for (int r = 0; r < 8; ++r) {
        int e = r * 64 + L;
        xr[r] = (e >= 128 && e < 384) ? frow[e - 128] : 0.0f;
        xi[r] = 0.0f;
    }
    fft512_inv_lds(xr, xi, trig, L);
    // forward FFT of real input = conj(inverse FFT)
    float2* Rrow = R + ((size_t)b * NOUT + x) * NOUT;
#pragma unroll
    for (int r = 0; r < 8; ++r) {
        int e = r * 64 + L;
        int k = __brev((unsigned)e) >> 23;
        Rrow[k] = make_float2(xr[r], -xi[r]);
    }
}

// ---------------- initial forward FFT, pass 2: columns (axis x) -> A0[b][p][q] --------------------
__global__ __launch_bounds__(256) void f2_kernel(const float2* __restrict__ R,
                                                 float2* __restrict__ A0) {
    __shared__ float2 trig[256];
    const int tid = threadIdx.x;
    init_trig(trig, tid);
    __syncthreads();
    const int w = tid >> 6, L = tid & 63;
    const int q = blockIdx.x * 4 + w;         // 0..511
    const int b = blockIdx.y;
    float xr[8], xi[8];
#pragma unroll
    for (int r = 0; r < 8; ++r) {
        int e = r * 64 + L;
        float2 v = R[((size_t)b * NOUT + e) * NOUT + q];
        xr[r] = v.x;
        xi[r] = -v.y;   // conj input
    }
    fft512_inv_lds(xr, xi, trig, L);
#pragma unroll
    for (int r = 0; r < 8; ++r) {
        int e = r * 64 + L;
        int p = __brev((unsigned)e) >> 23;
        A0[((size_t)b * NOUT + p) * NOUT + q] = make_float2(xr[r], -xi[r]); // conj output
    }
}

// ---------------- time-chunk simulation: register-resident state ----------------------------------
// block = (row group g of 4 rows, batch b); wave w owns row p = 4g + w.
// Each wave also owns sensors j = 64w + L and writes its block-final partial (j == tid).
__global__ __launch_bounds__(256, 4) void sim_kernel(
    const float* __restrict__ fil,
    const int* __restrict__ idx0, const int* __restrict__ idx1,
    float2* __restrict__ stateCur, float2* __restrict__ statePrev,
    float* __restrict__ partial, int Tc, int firstChunk)
{
    __shared__ float2 T[4][NOUT];        // 16384 B : per-row inverse-DFT result (bitrev positions)
    __shared__ float2 trig[256];         //  2048 B : init-time twiddle/phase source

    const int tid = threadIdx.x;
    const int w = tid >> 6, L = tid & 63;
    const int g = blockIdx.x, b = blockIdx.y;
    const int p = g * 4 + w;

    init_trig(trig, tid);
    __syncthreads();

    // --- hoist per-lane FFT twiddles into registers (constant across time steps) ---
    float2 tw0[4];
#pragma unroll
    for (int r = 0; r < 4; ++r) tw0[r] = trig[(r << 6) + L];
    float2 tw1a = trig[L << 1];
    float2 tw1b = trig[(64 + L) << 1];
    float2 tw2  = trig[L << 2];
    float2 tws[6];
    float  sgs[6];
#pragma unroll
    for (int s = 3; s <= 8; ++s) {
        const int half = 512 >> (s + 1);
        const int ex = (L & (half - 1)) << s;
        const bool hi = (L & half) != 0;
        float2 wv = trig[ex];
        tws[s - 3] = hi ? wv : make_float2(1.0f, 0.0f);
        sgs[s - 3] = hi ? -1.0f : 1.0f;
    }

    // --- sensor constants for this lane's sensor j = tid: gather position + 4 phase factors ---
    const int j = tid;
    const int su = idx0[j];
    const int spos = (int)(__brev((unsigned)idx1[j]) >> 23);
    float2 phw[4];
#pragma unroll
    for (int ww = 0; ww < 4; ++ww) {
        int m = ((g * 4 + ww) * su) & 511;
        float2 ph = trig[m & 255];
        phw[ww] = (m & 256) ? make_float2(-ph.x, -ph.y) : ph;
    }

    // --- load state + filter into registers ---
    float ar[8], ai[8], br[8], bi[8], C[8];
    {
        const size_t rowBase = ((size_t)b * NOUT + p) * NOUT;
        const float* filRow = fil + (size_t)p * NOUT;
#pragma unroll
        for (int r = 0; r < 8; ++r) {
            int e = r * 64 + L;
            float2 a0 = stateCur[rowBase + e];
            ar[r] = a0.x; ai[r] = a0.y;
            float2 a1 = firstChunk ? a0 : statePrev[rowBase + e];
            br[r] = a1.x; bi[r] = a1.y;
            C[r] = fmaf(-4.0f, filRow[e], 2.0f);
        }
    }
    __syncthreads();   // trig reads above complete before loop (also orders nothing else)

    float* pOut = partial + ((size_t)g * Tc * NB + b) * NPHI + j;
    for (int tl = 0; tl < Tc; ++tl) {
        // 3-term recurrence in registers: new = C*cur - prev; shift
        float xr[8], xi[8];
#pragma unroll
        for (int r = 0; r < 8; ++r) {
            float nr = fmaf(C[r], ar[r], -br[r]);
            float ni = fmaf(C[r], ai[r], -bi[r]);
            br[r] = ar[r]; bi[r] = ai[r];
            ar[r] = nr;    ai[r] = ni;
            xr[r] = nr;    xi[r] = ni;
        }
        fft512_inv_reg(xr, xi, tw0, tw1a, tw1b, tw2, tws, sgs);
        __syncthreads();   // previous step's gathers done before overwriting T
#pragma unroll
        for (int r = 0; r < 8; ++r) T[w][r * 64 + L] = make_float2(xr[r], xi[r]);
        __syncthreads();   // T complete before gathers
        // this lane's sensor: sum contributions of the block's 4 rows
        float acc;
        {
            float2 t0 = T[0][spos];
            float2 t1 = T[1][spos];
            float2 t2 = T[2][spos];
            float2 t3 = T[3][spos];
            acc  = fmaf(t0.x, phw[0].x, -t0.y * phw[0].y);
            acc  = fmaf(t1.x, phw[1].x, fmaf(-t1.y, phw[1].y, acc));
            acc  = fmaf(t2.x, phw[2].x, fmaf(-t2.y, phw[2].y, acc));
            acc  = fmaf(t3.x, phw[3].x, fmaf(-t3.y, phw[3].y, acc));
        }
        pOut[(size_t)tl * NB * NPHI] = acc;
    }

    // --- save state for next chunk ---
    {
        const size_t rowBase = ((size_t)b * NOUT + p) * NOUT;
#pragma unroll
        for (int r = 0; r < 8; ++r) {
            int e = r * 64 + L;
            stateCur[rowBase + e]  = make_float2(ar[r], ai[r]);
            statePrev[rowBase + e] = make_float2(br[r], bi[r]);
        }
    }
}

// ---------------- reduce 128 row-group partials -> out[b][j][t] -----------------------------------
__global__ __launch_bounds__(256) void reduce_kernel(const float* __restrict__ partial,
                                                     float* __restrict__ out,
                                                     int Tc, int tStart) {
    int id = blockIdx.x * 256 + threadIdx.x;   // over Tc*16*256, exact
    int j = id & 255;
    int b = (id >> 8) & 15;
    int tl = id >> 12;
    float s = 0.0f;
#pragma unroll 8
    for (int gg = 0; gg < 128; ++gg)
        s += partial[(((size_t)gg * Tc + tl) * NB + b) * NPHI + j];
    out[((size_t)b * NPHI + j) * NT + (tStart + tl)] = s * (1.0f / (512.0f * 512.0f));
}

extern "C" void kernel_launch(void* const* d_in, const int* in_sizes, int n_in,
                              void* d_out, int out_size, void* d_ws, size_t ws_size,
                              hipStream_t stream) {
    (void)in_sizes; (void)n_in; (void)out_size;
    const float* f   = (const float*)d_in[0];   // [16,1,256,256]
    const float* fil = (const float*)d_in[1];   // [512,512]
    const int* idx0  = (const int*)d_in[2];     // [256]
    const int* idx1  = (const int*)d_in[3];     // [256]
    float* out = (float*)d_out;                 // [16,1,256,240]

    char* ws = (char*)d_ws;
    const size_t stateBytes = (size_t)NB * NOUT * NOUT * sizeof(float2);  // 33.55 MB
    float2* stateCur  = (float2*)ws;
    float2* statePrev = (float2*)(ws + stateBytes);   // also reused as R scratch for f1/f2
    float*  partial   = (float*)(ws + 2 * stateBytes);
    size_t remain = (ws_size > 2 * stateBytes) ? ws_size - 2 * stateBytes : 0;

    // choose largest time chunk whose partial buffer fits in remaining workspace
    static const int tcs[] = {240, 120, 80, 60, 48, 40, 30, 24, 20, 16, 12, 10, 8, 6, 4, 2, 1};
    int Tc = 1;
    for (int i = 0; i < 17; ++i) {
        size_t need = (size_t)128 * tcs[i] * NB * NPHI * sizeof(float);
        if (need <= remain) { Tc = tcs[i]; break; }
    }

    hipMemsetAsync(statePrev, 0, stateBytes, stream);                 // zero-padded rows of R
    f1_kernel<<<dim3(64, NB), 256, 0, stream>>>(f, statePrev);        // rows x in [128,384)
    f2_kernel<<<dim3(128, NB), 256, 0, stream>>>(statePrev, stateCur);
    for (int t0 = 0; t0 < NT; t0 += Tc) {
        sim_kernel<<<dim3(128, NB), 256, 0, stream>>>(fil, idx0, idx1, stateCur, statePrev,
                                                      partial, Tc, t0 == 0 ? 1 : 0);
        reduce_kernel<<<dim3(Tc * NB), 256, 0, stream>>>(partial, out, Tc, t0);
    }
}

// Round 3
// 1796.996 us; speedup vs baseline: 2.0248x; 1.6455x over previous
//
#include <hip/hip_runtime.h>
#include <hip/hip_bf16.h>

// WaveOperator: Fourier-domain 3-term recurrence + per-row inverse FFT sampling.
// A_{t+1}(p,q) = (2-4*fil(p,q)) * A_t - A_{t-1};  y[b,j,t] = Re(ifft2(A_{t+1})[u_j,v_j])
// R3: 512-pt row IFFT as 8x8x8 four-step: three 8-pt REGISTER DFTs with two in-wave LDS
// transposes (b128 writes / b64 reads, bank-optimal pitches). No cross-lane shuffles in the
// hot loop -> DS-pipe ops per wave-step drop 108 -> 32.

#define NOUT 512
#define NB 16
#define NPHI 256
#define NT 240

// per-wave LDS region: A (transpose-1 scratch, aliased by final T) = 64 rows * 80B = 5120,
// B (transpose-2 scratch) = 8*528 + 7*64 + 64 = 4208 -> pad 4224. Total 9344 per wave.
#define WREG 9344
#define AOFF 0
#define BOFF 5120

struct cplx { float r, i; };
__device__ __forceinline__ cplx cadd(cplx a, cplx b) { return {a.r + b.r, a.i + b.i}; }
__device__ __forceinline__ cplx csub(cplx a, cplx b) { return {a.r - b.r, a.i - b.i}; }
__device__ __forceinline__ cplx cmul(cplx a, cplx b) {
    return {fmaf(a.r, b.r, -a.i * b.i), fmaf(a.r, b.i, a.i * b.r)};
}
__device__ __forceinline__ cplx cmuli(cplx a) { return {-a.i, a.r}; }                 // * i
__device__ __forceinline__ cplx cmulw8(cplx a) {                                      // * (s+is)
    const float s = 0.70710678118654752f; return {s * (a.r - a.i), s * (a.r + a.i)};
}
__device__ __forceinline__ cplx cmulw83(cplx a) {                                     // * (-s+is)
    const float s = 0.70710678118654752f; return {-s * (a.r + a.i), s * (a.r - a.i)};
}

// 8-pt DFT, positive exponent (inverse convention): Y[k] = sum_r y[r] * exp(+2pi i rk/8)
__device__ __forceinline__ void dft8p(const cplx y[8], cplx Y[8]) {
    cplx t0 = cadd(y[0], y[4]), t4 = csub(y[0], y[4]);
    cplx t1 = cadd(y[1], y[5]), t5 = cmulw8(csub(y[1], y[5]));
    cplx t2 = cadd(y[2], y[6]), t6 = cmuli(csub(y[2], y[6]));
    cplx t3 = cadd(y[3], y[7]), t7 = cmulw83(csub(y[3], y[7]));
    cplx u0 = cadd(t0, t2), u2 = csub(t0, t2);
    cplx u1 = cadd(t1, t3), u3 = cmuli(csub(t1, t3));
    Y[0] = cadd(u0, u1); Y[4] = csub(u0, u1);
    Y[2] = cadd(u2, u3); Y[6] = csub(u2, u3);
    cplx v0 = cadd(t4, t6), v2 = csub(t4, t6);
    cplx v1 = cadd(t5, t7), v3 = cmuli(csub(t5, t7));
    Y[1] = cadd(v0, v1); Y[5] = csub(v0, v1);
    Y[3] = cadd(v2, v3); Y[7] = csub(v2, v3);
}

__device__ __forceinline__ void init_trig(float2* trig, int tid) {
    if (tid < 256) {
        float ang = (float)tid * (6.283185307179586f / 512.0f);
        float s, c;
        sincosf(ang, &s, &c);
        trig[tid] = make_float2(c, s);
    }
}

// W512^m from the half-table
__device__ __forceinline__ cplx wlookup(const float2* trig, int m) {
    m &= 511;
    float2 ph = trig[m & 255];
    return (m & 256) ? cplx{-ph.x, -ph.y} : cplx{ph.x, ph.y};
}

// ---------------- init kernels keep the old shuffle FFT (run once, not hot) ----------------------
__device__ __forceinline__ void cbfly(float& ar, float& ai, float& br, float& bi,
                                      float wr, float wi) {
    float dr = ar - br, di = ai - bi;
    ar = ar + br; ai = ai + bi;
    br = fmaf(dr, wr, -di * wi);
    bi = fmaf(dr, wi,  di * wr);
}

__device__ __forceinline__ void fft512_inv_lds(float* xr, float* xi, const float2* trig, int L) {
#pragma unroll
    for (int r = 0; r < 4; ++r) {
        float2 w = trig[(r << 6) + L];
        cbfly(xr[r], xi[r], xr[r + 4], xi[r + 4], w.x, w.y);
    }
    {
        float2 w0 = trig[L << 1];
        float2 w1 = trig[(64 + L) << 1];
        cbfly(xr[0], xi[0], xr[2], xi[2], w0.x, w0.y);
        cbfly(xr[1], xi[1], xr[3], xi[3], w1.x, w1.y);
        cbfly(xr[4], xi[4], xr[6], xi[6], w0.x, w0.y);
        cbfly(xr[5], xi[5], xr[7], xi[7], w1.x, w1.y);
    }
    {
        float2 w = trig[L << 2];
        cbfly(xr[0], xi[0], xr[1], xi[1], w.x, w.y);
        cbfly(xr[2], xi[2], xr[3], xi[3], w.x, w.y);
        cbfly(xr[4], xi[4], xr[5], xi[5], w.x, w.y);
        cbfly(xr[6], xi[6], xr[7], xi[7], w.x, w.y);
    }
#pragma unroll
    for (int s = 3; s <= 8; ++s) {
        const int half = 512 >> (s + 1);
        const int ex = (L & (half - 1)) << s;
        float2 w = trig[ex];
        const bool hi = (L & half) != 0;
        float wr = hi ? w.x : 1.0f;
        float wi = hi ? w.y : 0.0f;
        float sg = hi ? -1.0f : 1.0f;
#pragma unroll
        for (int r = 0; r < 8; ++r) {
            float orv = __shfl_xor(xr[r], half);
            float oiv = __shfl_xor(xi[r], half);
            float tr = fmaf(sg, xr[r], orv);
            float ti = fmaf(sg, xi[r], oiv);
            xr[r] = fmaf(tr, wr, -ti * wi);
            xi[r] = fmaf(tr, wi,  ti * wr);
        }
    }
}

__global__ __launch_bounds__(256) void f1_kernel(const float* __restrict__ f,
                                                 float2* __restrict__ R) {
    __shared__ float2 trig[256];
    const int tid = threadIdx.x;
    init_trig(trig, tid);
    __syncthreads();
    const int w = tid >> 6, L = tid & 63;
    const int x = 128 + blockIdx.x * 4 + w;   // nonzero rows only: [128, 384)
    const int b = blockIdx.y;
    const float* frow = f + ((size_t)b * 256 + (x - 128)) * 256;
    float xr[8], xi[8];
#pragma unroll
    for (int r = 0; r < 8; ++r) {
        int e = r * 64 + L;
        xr[r] = (e >= 128 && e < 384) ? frow[e - 128] : 0.0f;
        xi[r] = 0.0f;
    }
    fft512_inv_lds(xr, xi, trig, L);
    float2* Rrow = R + ((size_t)b * NOUT + x) * NOUT;
#pragma unroll
    for (int r = 0; r < 8; ++r) {
        int e = r * 64 + L;
        int k = __brev((unsigned)e) >> 23;
        Rrow[k] = make_float2(xr[r], -xi[r]);
    }
}

__global__ __launch_bounds__(256) void f2_kernel(const float2* __restrict__ R,
                                                 float2* __restrict__ A0) {
    __shared__ float2 trig[256];
    const int tid = threadIdx.x;
    init_trig(trig, tid);
    __syncthreads();
    const int w = tid >> 6, L = tid & 63;
    const int q = blockIdx.x * 4 + w;
    const int b = blockIdx.y;
    float xr[8], xi[8];
#pragma unroll
    for (int r = 0; r < 8; ++r) {
        int e = r * 64 + L;
        float2 v = R[((size_t)b * NOUT + e) * NOUT + q];
        xr[r] = v.x;
        xi[r] = -v.y;
    }
    fft512_inv_lds(xr, xi, trig, L);
#pragma unroll
    for (int r = 0; r < 8; ++r) {
        int e = r * 64 + L;
        int p = __brev((unsigned)e) >> 23;
        A0[((size_t)b * NOUT + p) * NOUT + q] = make_float2(xr[r], -xi[r]);
    }
}

// ---------------- time-chunk simulation ----------------------------------------------------------
// block = (row group g of 4 rows, batch b); wave w owns row p = 4g + w.
// 512-pt inverse DFT per row per step via 8x8x8 four-step, all exchanges through per-wave LDS.
// Element n = 64r + L (r=reg, L=lane). k = k1 + 8*m1 + 64*m2.
//   G[k1,L]   = dft8 over r;            G' = G * W512^{L*k1}        (tA)
//   transpose1: lane role (k1=L>>3, c=L&7) gets G'[k1, c+8a] in reg a
//   H[k1,m1,c] = dft8 over a;           H' = H * W512^{8*c*m1}      (tB)
//   transpose2: lane role (k1, m1) gets H'[k1,m1,c] in reg c
//   X[k1+8m1+64m2] = dft8 over c; stored at T[(k1*8+m1)*80 + m2*8] (aliases transpose-1 scratch)
__global__ __launch_bounds__(256, 4) void sim_kernel(
    const float* __restrict__ fil,
    const int* __restrict__ idx0, const int* __restrict__ idx1,
    float2* __restrict__ stateCur, float2* __restrict__ statePrev,
    float* __restrict__ partial, int Tc, int firstChunk)
{
    __shared__ __align__(16) char waveMem[4 * WREG];   // 37376 B
    __shared__ float2 trig[256];                       //  2048 B -> total 39424 B

    const int tid = threadIdx.x;
    const int w = tid >> 6, L = tid & 63;
    const int g = blockIdx.x, b = blockIdx.y;
    const int p = g * 4 + w;
    const int k1L = L >> 3, cL = L & 7;

    init_trig(trig, tid);
    __syncthreads();

    // --- per-lane constant twiddles ---
    cplx tA[8], tB[8];
#pragma unroll
    for (int k1 = 1; k1 < 8; ++k1) tA[k1] = wlookup(trig, L * k1);
#pragma unroll
    for (int m1 = 1; m1 < 8; ++m1) tB[m1] = wlookup(trig, 8 * cL * m1);

    // --- sensor constants for this lane's sensor j = tid ---
    const int j = tid;
    const int su = idx0[j];
    int sposByte;
    {
        int v = idx1[j];
        int Mp = (v & 7) * 8 + ((v >> 3) & 7);
        sposByte = Mp * 80 + (v >> 6) * 8;
    }
    float2 phw[4];
#pragma unroll
    for (int ww = 0; ww < 4; ++ww) {
        cplx ph = wlookup(trig, (g * 4 + ww) * su);
        phw[ww] = make_float2(ph.r, ph.i);
    }

    // --- LDS bases (per-lane, all further addressing via immediate offsets) ---
    char* myA   = waveMem + w * WREG + AOFF;
    char* myB   = waveMem + w * WREG + BOFF;
    char* awBase = myA + L * 80;                 // transpose-1 write base; also final T write base
    char* arBase = myA + cL * 80 + k1L * 8;      // transpose-1 read base (offsets a*640)
    char* bwBase = myB + k1L * 528 + cL * 64;    // transpose-2 write base (offsets 0..48)
    char* brBase = myB + k1L * 528 + cL * 8;     // transpose-2 read base (offsets c*64); m1==cL
    const char* gBase = waveMem + sposByte;      // gather base (offsets w*WREG)

    // --- load state + filter into registers ---
    float ar[8], ai[8], br[8], bi[8], C[8];
    {
        const size_t rowBase = ((size_t)b * NOUT + p) * NOUT;
        const float* filRow = fil + (size_t)p * NOUT;
#pragma unroll
        for (int r = 0; r < 8; ++r) {
            int e = r * 64 + L;
            float2 a0 = stateCur[rowBase + e];
            ar[r] = a0.x; ai[r] = a0.y;
            float2 a1 = firstChunk ? a0 : statePrev[rowBase + e];
            br[r] = a1.x; bi[r] = a1.y;
            C[r] = fmaf(-4.0f, filRow[e], 2.0f);
        }
    }

    float* pOut = partial + ((size_t)g * Tc * NB + b) * NPHI + j;
    for (int tl = 0; tl < Tc; ++tl) {
        // 3-term recurrence in registers
        cplx y[8];
#pragma unroll
        for (int r = 0; r < 8; ++r) {
            float nr = fmaf(C[r], ar[r], -br[r]);
            float ni = fmaf(C[r], ai[r], -bi[r]);
            br[r] = ar[r]; bi[r] = ai[r];
            ar[r] = nr;    ai[r] = ni;
            y[r].r = nr;   y[r].i = ni;
        }
        // stage 1: dft8 over registers + tA twiddle
        cplx G[8];
        dft8p(y, G);
#pragma unroll
        for (int k1 = 1; k1 < 8; ++k1) G[k1] = cmul(G[k1], tA[k1]);

        __syncthreads();   // barrier alpha: prior step's gathers done before scratch reuse

        // transpose 1: write contiguous (b128 x4), read strided (b64 x8)
        *(float4*)(awBase +  0) = make_float4(G[0].r, G[0].i, G[1].r, G[1].i);
        *(float4*)(awBase + 16) = make_float4(G[2].r, G[2].i, G[3].r, G[3].i);
        *(float4*)(awBase + 32) = make_float4(G[4].r, G[4].i, G[5].r, G[5].i);
        *(float4*)(awBase + 48) = make_float4(G[6].r, G[6].i, G[7].r, G[7].i);
        cplx ga[8];
#pragma unroll
        for (int a = 0; a < 8; ++a) {
            float2 v = *(const float2*)(arBase + a * 640);
            ga[a] = {v.x, v.y};
        }
        // stage 2: dft8 over a + tB twiddle
        cplx H[8];
        dft8p(ga, H);
#pragma unroll
        for (int m1 = 1; m1 < 8; ++m1) H[m1] = cmul(H[m1], tB[m1]);

        // transpose 2
        *(float4*)(bwBase +  0) = make_float4(H[0].r, H[0].i, H[1].r, H[1].i);
        *(float4*)(bwBase + 16) = make_float4(H[2].r, H[2].i, H[3].r, H[3].i);
        *(float4*)(bwBase + 32) = make_float4(H[4].r, H[4].i, H[5].r, H[5].i);
        *(float4*)(bwBase + 48) = make_float4(H[6].r, H[6].i, H[7].r, H[7].i);
        cplx hc[8];
#pragma unroll
        for (int c2 = 0; c2 < 8; ++c2) {
            float2 v = *(const float2*)(brBase + c2 * 64);
            hc[c2] = {v.x, v.y};
        }
        // stage 3: dft8 over c -> final X, store to T (aliases transpose-1 scratch)
        cplx X[8];
        dft8p(hc, X);
        *(float4*)(awBase +  0) = make_float4(X[0].r, X[0].i, X[1].r, X[1].i);
        *(float4*)(awBase + 16) = make_float4(X[2].r, X[2].i, X[3].r, X[3].i);
        *(float4*)(awBase + 32) = make_float4(X[4].r, X[4].i, X[5].r, X[5].i);
        *(float4*)(awBase + 48) = make_float4(X[6].r, X[6].i, X[7].r, X[7].i);

        __syncthreads();   // barrier beta: T complete before gathers

        // this lane's sensor: sum contributions of the block's 4 rows
        float2 q0 = *(const float2*)(gBase);
        float2 q1 = *(const float2*)(gBase + WREG);
        float2 q2 = *(const float2*)(gBase + 2 * WREG);
        float2 q3 = *(const float2*)(gBase + 3 * WREG);
        float acc;
        acc = fmaf(q0.x, phw[0].x, -q0.y * phw[0].y);
        acc = fmaf(q1.x, phw[1].x, fmaf(-q1.y, phw[1].y, acc));
        acc = fmaf(q2.x, phw[2].x, fmaf(-q2.y, phw[2].y, acc));
        acc = fmaf(q3.x, phw[3].x, fmaf(-q3.y, phw[3].y, acc));
        pOut[(size_t)tl * NB * NPHI] = acc;
    }

    // --- save state for next chunk ---
    {
        const size_t rowBase = ((size_t)b * NOUT + p) * NOUT;
#pragma unroll
        for (int r = 0; r < 8; ++r) {
            int e = r * 64 + L;
            stateCur[rowBase + e]  = make_float2(ar[r], ai[r]);
            statePrev[rowBase + e] = make_float2(br[r], bi[r]);
        }
    }
}

// ---------------- reduce 128 row-group partials -> out[b][j][t] -----------------------------------
__global__ __launch_bounds__(256) void reduce_kernel(const float* __restrict__ partial,
                                                     float* __restrict__ out,
                                                     int Tc, int tStart) {
    int id = blockIdx.x * 256 + threadIdx.x;   // over Tc*16*256, exact
    int j = id & 255;
    int b = (id >> 8) & 15;
    int tl = id >> 12;
    float s = 0.0f;
#pragma unroll 8
    for (int gg = 0; gg < 128; ++gg)
        s += partial[(((size_t)gg * Tc + tl) * NB + b) * NPHI + j];
    out[((size_t)b * NPHI + j) * NT + (tStart + tl)] = s * (1.0f / (512.0f * 512.0f));
}

extern "C" void kernel_launch(void* const* d_in, const int* in_sizes, int n_in,
                              void* d_out, int out_size, void* d_ws, size_t ws_size,
                              hipStream_t stream) {
    (void)in_sizes; (void)n_in; (void)out_size;
    const float* f   = (const float*)d_in[0];   // [16,1,256,256]
    const float* fil = (const float*)d_in[1];   // [512,512]
    const int* idx0  = (const int*)d_in[2];     // [256]
    const int* idx1  = (const int*)d_in[3];     // [256]
    float* out = (float*)d_out;                 // [16,1,256,240]

    char* ws = (char*)d_ws;
    const size_t stateBytes = (size_t)NB * NOUT * NOUT * sizeof(float2);  // 33.55 MB
    float2* stateCur  = (float2*)ws;
    float2* statePrev = (float2*)(ws + stateBytes);   // also reused as R scratch for f1/f2
    float*  partial   = (float*)(ws + 2 * stateBytes);
    size_t remain = (ws_size > 2 * stateBytes) ? ws_size - 2 * stateBytes : 0;

    // choose largest time chunk whose partial buffer fits in remaining workspace
    static const int tcs[] = {240, 120, 80, 60, 48, 40, 30, 24, 20, 16, 12, 10, 8, 6, 4, 2, 1};
    int Tc = 1;
    for (int i = 0; i < 17; ++i) {
        size_t need = (size_t)128 * tcs[i] * NB * NPHI * sizeof(float);
        if (need <= remain) { Tc = tcs[i]; break; }
    }

    hipMemsetAsync(statePrev, 0, stateBytes, stream);                 // zero-padded rows of R
    f1_kernel<<<dim3(64, NB), 256, 0, stream>>>(f, statePrev);        // rows x in [128,384)
    f2_kernel<<<dim3(128, NB), 256, 0, stream>>>(statePrev, stateCur);
    for (int t0 = 0; t0 < NT; t0 += Tc) {
        sim_kernel<<<dim3(128, NB), 256, 0, stream>>>(fil, idx0, idx1, stateCur, statePrev,
                                                      partial, Tc, t0 == 0 ? 1 : 0);
        reduce_kernel<<<dim3(Tc * NB), 256, 0, stream>>>(partial, out, Tc, t0);
    }
}